// Round 6
// baseline (231.112 us; speedup 1.0000x reference)
//
#include <hip/hip_runtime.h>

// Integrate-and-fire scan: x_seq (T=64, 128, 4096) f32 -> s_seq same shape.
//   v += x[t]; s = (v >= 1.0f); v -= s;
// R1-R4: compiler emits load->vmcnt(0)->use->store per t-step; the vmcnt(0)
// drains the prior STORE to memory too -> serial ~1us/step -> 80us, 2.5 TB/s.
// R5: split-asm vmcnt(7) pipeline was UNSOUND (mixed load/store retirement +
// compiler register copies in the window between load-asm and waitcnt-asm).
// R6: all 8 loads + s_waitcnt vmcnt(0) in ONE asm block: when the block exits,
// data has landed -> no hazard window, no mixed-order assumptions. The drain
// also retires the previous batch's stores; store-data quads are threaded
// through the load block as "+v" passthroughs so regalloc can't reuse them
// while their store is outstanding. MLP = 8x1KB/wave, 8 waves/CU.

#define TSTEPS 64
#define NCOLS  (128 * 4096)      // 524288 columns
#define NCOLS4 (NCOLS / 4)       // 131072 float4 column-groups
#define BATCH  8
// t-stride for one column group = NCOLS*4 bytes = 2 MiB = 0x200000.

typedef float v4f __attribute__((ext_vector_type(4)));

#define LOAD8_AND_WAIT()                                                      \
    asm volatile(                                                             \
        "global_load_dwordx4 %0, %[off], %[base]\n\t"                         \
        "v_add_u32 %[off], 0x200000, %[off]\n\t"                              \
        "global_load_dwordx4 %1, %[off], %[base]\n\t"                         \
        "v_add_u32 %[off], 0x200000, %[off]\n\t"                              \
        "global_load_dwordx4 %2, %[off], %[base]\n\t"                         \
        "v_add_u32 %[off], 0x200000, %[off]\n\t"                              \
        "global_load_dwordx4 %3, %[off], %[base]\n\t"                         \
        "v_add_u32 %[off], 0x200000, %[off]\n\t"                              \
        "global_load_dwordx4 %4, %[off], %[base]\n\t"                         \
        "v_add_u32 %[off], 0x200000, %[off]\n\t"                              \
        "global_load_dwordx4 %5, %[off], %[base]\n\t"                         \
        "v_add_u32 %[off], 0x200000, %[off]\n\t"                              \
        "global_load_dwordx4 %6, %[off], %[base]\n\t"                         \
        "v_add_u32 %[off], 0x200000, %[off]\n\t"                              \
        "global_load_dwordx4 %7, %[off], %[base]\n\t"                         \
        "v_add_u32 %[off], 0x200000, %[off]\n\t"                              \
        "s_waitcnt vmcnt(0)"                                                  \
        : "=&v"(d0), "=&v"(d1), "=&v"(d2), "=&v"(d3),                         \
          "=&v"(d4), "=&v"(d5), "=&v"(d6), "=&v"(d7),                         \
          [off] "+v"(voff_l),                                                 \
          /* keep prior-batch store data alive until the drain above: */      \
          "+v"(s0), "+v"(s1), "+v"(s2), "+v"(s3),                             \
          "+v"(s4), "+v"(s5), "+v"(s6), "+v"(s7)                              \
        : [base] "s"(x)                                                       \
        : "memory")

#define CONSUME_STORE(dj, sj)                                                 \
    do {                                                                      \
        vx += dj.x; vy += dj.y; vz += dj.z; vw += dj.w;                       \
        sj.x = (vx >= 1.0f) ? 1.0f : 0.0f;                                    \
        sj.y = (vy >= 1.0f) ? 1.0f : 0.0f;                                    \
        sj.z = (vz >= 1.0f) ? 1.0f : 0.0f;                                    \
        sj.w = (vw >= 1.0f) ? 1.0f : 0.0f;                                    \
        vx -= sj.x; vy -= sj.y; vz -= sj.z; vw -= sj.w;                       \
        asm volatile(                                                         \
            "global_store_dwordx4 %[off], %[dat], %[base]\n\t"                \
            "v_add_u32 %[off], 0x200000, %[off]"                              \
            : [off] "+v"(voff_s)                                              \
            : [dat] "v"(sj), [base] "s"(out)                                  \
            : "memory");                                                      \
    } while (0)

__global__ __launch_bounds__(256, 2) void TandemIF_86096914416163_kernel(
    const float* __restrict__ x, float* __restrict__ out)
{
    const int c = blockIdx.x * 256 + threadIdx.x;   // grid sized exactly

    unsigned voff_l = (unsigned)c * 16u;   // byte offset from x base (max 128 MiB, fits u32)
    unsigned voff_s = (unsigned)c * 16u;   // byte offset from out base

    float vx = 0.0f, vy = 0.0f, vz = 0.0f, vw = 0.0f;
    v4f d0, d1, d2, d3, d4, d5, d6, d7;
    v4f s0 = {0,0,0,0}, s1 = {0,0,0,0}, s2 = {0,0,0,0}, s3 = {0,0,0,0};
    v4f s4 = {0,0,0,0}, s5 = {0,0,0,0}, s6 = {0,0,0,0}, s7 = {0,0,0,0};

    for (int tb = 0; tb < TSTEPS / BATCH; ++tb) {
        LOAD8_AND_WAIT();          // 8 loads in flight, then full drain
        CONSUME_STORE(d0, s0);
        CONSUME_STORE(d1, s1);
        CONSUME_STORE(d2, s2);
        CONSUME_STORE(d3, s3);
        CONSUME_STORE(d4, s4);
        CONSUME_STORE(d5, s5);
        CONSUME_STORE(d6, s6);
        CONSUME_STORE(d7, s7);
    }
}

extern "C" void kernel_launch(void* const* d_in, const int* in_sizes, int n_in,
                              void* d_out, int out_size, void* d_ws, size_t ws_size,
                              hipStream_t stream)
{
    const float* x = (const float*)d_in[0];
    float* out     = (float*)d_out;
    // 131072 float4 columns / 256 threads = 512 blocks (2 blocks/CU, 8 waves/CU)
    TandemIF_86096914416163_kernel<<<dim3(NCOLS4 / 256), dim3(256), 0, stream>>>(x, out);
}

// Round 7
// 228.113 us; speedup vs baseline: 1.0131x; 1.0131x over previous
//
#include <hip/hip_runtime.h>

// Integrate-and-fire scan: x_seq (T=64, 128, 4096) f32 -> s_seq same shape.
//   v += x[t]; s = (v >= 1.0f); v -= s;
// R1-R6 all ~80us / 2.5 TB/s. Root cause: every prior structure waits (directly
// or via compiler vmcnt(0)) on the PREVIOUS STORES before consuming loads ->
// per-iteration serial exposure of max(load,store-commit) latency, chip-wide
// phasing. R7: full software pipeline in ONE asm block with fixed physical
// registers (no compiler interference possible):
//   issue L(k+1); s_waitcnt vmcnt(16); consume(k) + issue S(k)
// vmcnt pops in issue order, so vmcnt(16) retires exactly through L(k) while
// S(k-1)[8] + L(k+1)[8] stay in flight -> stores never gate anything.
// Hazard proofs:
//  - load buf: L(k) lands in dA (k even) / dB (k odd); dA rewritten by L(k+2)
//    at iter k+1 top, consumed at iter k (before) -> safe.
//  - store buf: S(k) data in sA (k even)/sB (k odd); rewritten at consume(k+2),
//    which is after w(k+2)=vmcnt(16) leaving only S(k+1)+L(k+3) -> S(k) popped.
//  - edge waits: k=0 -> vmcnt(8) (outstanding L1 only after L0 pops);
//    k=7 -> vmcnt(8) (no L8; S6 remains).
//  - no trailing wait needed: fire-and-forget stores complete after s_endpgm.
// Register map (fixed, clobbered): v8-11 = vx..vw, v12 = load voff,
// v13 = store voff, v14 = 1.0f, dA=v[32:63], dB=v[64:95], sA=v[96:127],
// sB=v[128:159].

#define TSTEPS 64
#define NCOLS  (128 * 4096)      // 524288 columns
#define NCOLS4 (NCOLS / 4)       // 131072 float4 column-groups
// t-stride for one column group = NCOLS*4 bytes = 2 MiB = 0x200000.

#define LD1(Q)                                                        \
    "global_load_dwordx4 v[" Q "], v12, %[bx]\n\t"                    \
    "v_add_u32 v12, 0x200000, v12\n\t"

#define LOAD8_A                                                       \
    LD1("32:35") LD1("36:39") LD1("40:43") LD1("44:47")               \
    LD1("48:51") LD1("52:55") LD1("56:59") LD1("60:63")

#define LOAD8_B                                                       \
    LD1("64:67") LD1("68:71") LD1("72:75") LD1("76:79")               \
    LD1("80:83") LD1("84:87") LD1("88:91") LD1("92:95")

// Consume one landed quad (dx..dw) -> spikes into (sx..sw) -> store quad.
#define STEP(dx,dy,dz,dw, sx,sy,sz,sw, SQ)                            \
    "v_add_f32 v8, v8, v" dx "\n\t"                                   \
    "v_add_f32 v9, v9, v" dy "\n\t"                                   \
    "v_add_f32 v10, v10, v" dz "\n\t"                                 \
    "v_add_f32 v11, v11, v" dw "\n\t"                                 \
    "v_cmp_ge_f32 vcc, v8, v14\n\t"                                   \
    "v_cndmask_b32 v" sx ", 0, v14, vcc\n\t"                          \
    "v_cmp_ge_f32 vcc, v9, v14\n\t"                                   \
    "v_cndmask_b32 v" sy ", 0, v14, vcc\n\t"                          \
    "v_cmp_ge_f32 vcc, v10, v14\n\t"                                  \
    "v_cndmask_b32 v" sz ", 0, v14, vcc\n\t"                          \
    "v_cmp_ge_f32 vcc, v11, v14\n\t"                                  \
    "v_cndmask_b32 v" sw ", 0, v14, vcc\n\t"                          \
    "v_sub_f32 v8, v8, v" sx "\n\t"                                   \
    "v_sub_f32 v9, v9, v" sy "\n\t"                                   \
    "v_sub_f32 v10, v10, v" sz "\n\t"                                 \
    "v_sub_f32 v11, v11, v" sw "\n\t"                                 \
    "global_store_dwordx4 v13, v[" SQ "], %[bo]\n\t"                  \
    "v_add_u32 v13, 0x200000, v13\n\t"

#define CONSUME_A_SA                                                  \
    STEP("32","33","34","35",  "96","97","98","99",    "96:99")       \
    STEP("36","37","38","39",  "100","101","102","103","100:103")     \
    STEP("40","41","42","43",  "104","105","106","107","104:107")     \
    STEP("44","45","46","47",  "108","109","110","111","108:111")     \
    STEP("48","49","50","51",  "112","113","114","115","112:115")     \
    STEP("52","53","54","55",  "116","117","118","119","116:119")     \
    STEP("56","57","58","59",  "120","121","122","123","120:123")     \
    STEP("60","61","62","63",  "124","125","126","127","124:127")

#define CONSUME_B_SB                                                  \
    STEP("64","65","66","67",  "128","129","130","131","128:131")     \
    STEP("68","69","70","71",  "132","133","134","135","132:135")     \
    STEP("72","73","74","75",  "136","137","138","139","136:139")     \
    STEP("76","77","78","79",  "140","141","142","143","140:143")     \
    STEP("80","81","82","83",  "144","145","146","147","144:147")     \
    STEP("84","85","86","87",  "148","149","150","151","148:151")     \
    STEP("88","89","90","91",  "152","153","154","155","152:155")     \
    STEP("92","93","94","95",  "156","157","158","159","156:159")

__global__ __launch_bounds__(256) void TandemIF_86096914416163_kernel(
    const float* __restrict__ x, float* __restrict__ out)
{
    const int c = blockIdx.x * 256 + threadIdx.x;   // grid sized exactly
    const unsigned voff = (unsigned)c * 16u;        // byte offset (max 128 MiB)

    asm volatile(
        // ---- prolog: state init + L0 -> dA ----
        "v_mov_b32 v8, 0\n\t"
        "v_mov_b32 v9, 0\n\t"
        "v_mov_b32 v10, 0\n\t"
        "v_mov_b32 v11, 0\n\t"
        "v_mov_b32 v14, 1.0\n\t"
        "v_mov_b32 v12, %[voff]\n\t"
        "v_mov_b32 v13, %[voff]\n\t"
        LOAD8_A
        // ---- k=0: L1->dB, wait L0 (only L1 remains), consume dA -> sA ----
        LOAD8_B
        "s_waitcnt vmcnt(8)\n\t"
        CONSUME_A_SA
        // ---- k=1: L2->dA, wait L1 (S0+L2 remain = 16), consume dB -> sB ----
        LOAD8_A
        "s_waitcnt vmcnt(16)\n\t"
        CONSUME_B_SB
        // ---- k=2 ----
        LOAD8_B
        "s_waitcnt vmcnt(16)\n\t"
        CONSUME_A_SA
        // ---- k=3 ----
        LOAD8_A
        "s_waitcnt vmcnt(16)\n\t"
        CONSUME_B_SB
        // ---- k=4 ----
        LOAD8_B
        "s_waitcnt vmcnt(16)\n\t"
        CONSUME_A_SA
        // ---- k=5 ----
        LOAD8_A
        "s_waitcnt vmcnt(16)\n\t"
        CONSUME_B_SB
        // ---- k=6: L7->dB, wait L6 (S5+L7 = 16), consume dA -> sA ----
        LOAD8_B
        "s_waitcnt vmcnt(16)\n\t"
        CONSUME_A_SA
        // ---- k=7: no more loads; wait L7 (S6 remains = 8), consume dB ----
        "s_waitcnt vmcnt(8)\n\t"
        CONSUME_B_SB
        :
        : [voff] "v"(voff), [bx] "s"(x), [bo] "s"(out)
        : "memory", "vcc",
          "v8","v9","v10","v11","v12","v13","v14",
          "v32","v33","v34","v35","v36","v37","v38","v39",
          "v40","v41","v42","v43","v44","v45","v46","v47",
          "v48","v49","v50","v51","v52","v53","v54","v55",
          "v56","v57","v58","v59","v60","v61","v62","v63",
          "v64","v65","v66","v67","v68","v69","v70","v71",
          "v72","v73","v74","v75","v76","v77","v78","v79",
          "v80","v81","v82","v83","v84","v85","v86","v87",
          "v88","v89","v90","v91","v92","v93","v94","v95",
          "v96","v97","v98","v99","v100","v101","v102","v103",
          "v104","v105","v106","v107","v108","v109","v110","v111",
          "v112","v113","v114","v115","v116","v117","v118","v119",
          "v120","v121","v122","v123","v124","v125","v126","v127",
          "v128","v129","v130","v131","v132","v133","v134","v135",
          "v136","v137","v138","v139","v140","v141","v142","v143",
          "v144","v145","v146","v147","v148","v149","v150","v151",
          "v152","v153","v154","v155","v156","v157","v158","v159");
}

extern "C" void kernel_launch(void* const* d_in, const int* in_sizes, int n_in,
                              void* d_out, int out_size, void* d_ws, size_t ws_size,
                              hipStream_t stream)
{
    const float* x = (const float*)d_in[0];
    float* out     = (float*)d_out;
    // 131072 float4 columns / 256 threads = 512 blocks (2 blocks/CU, 8 waves/CU)
    TandemIF_86096914416163_kernel<<<dim3(NCOLS4 / 256), dim3(256), 0, stream>>>(x, out);
}